// Round 1
// baseline (143.071 us; speedup 1.0000x reference)
//
#include <hip/hip_runtime.h>
#include <hip/hip_bf16.h>

#define BB 64
#define NN 512
#define FF 64
#define KK 16
#define GG 32
#define TOPKN 4

// workspace layout (float offsets)
#define ROUTE_OFF 0                         // B*N*K       = 524288
#define E1C_OFF   (BB*NN*KK)                // 2*K*N*G     = 524288
#define E2S_OFF   (E1C_OFF + 2*KK*NN*GG)    // 2*K*G*N     = 524288
#define M_OFF     (E2S_OFF + 2*KK*GG*NN)    // B*K*64*F    = 4194304
// total ws floats = 5767168  (~23 MB)

// ---------------------------------------------------------------------------
// Kernel 1: router logits (fp64 accumulate for exact ordering), sigmoid,
// top-4 (descending, ties -> lowest index), normalized gate weights.
// grid 256 x block 128 : one thread per (b,n) row.
// ---------------------------------------------------------------------------
__global__ __launch_bounds__(128)
void router_kernel(const float* __restrict__ x, const float* __restrict__ rw,
                   const float* __restrict__ rb, const int* __restrict__ bias,
                   float* __restrict__ route, float* __restrict__ topk_out)
{
    __shared__ float rwl[KK * FF];
    __shared__ float rbl[KK];
    __shared__ float xl[128 * 65];   // +1 pad -> conflict-free column reads

    const int t = threadIdx.x;
    for (int i = t; i < KK * FF; i += 128) rwl[i] = rw[i];
    if (t < KK) rbl[t] = rb[t];

    // stage 128 rows of x (128*64 floats) coalesced
    const long base = (long)blockIdx.x * 128 * FF;
    const float4* src = (const float4*)(x + base);
    for (int q = 0; q < 16; ++q) {
        int idx = t + q * 128;           // 2048 float4
        float4 v = src[idx];
        int row = idx >> 4;              // 16 float4 per row
        int fo = (idx & 15) * 4;
        xl[row * 65 + fo + 0] = v.x;
        xl[row * 65 + fo + 1] = v.y;
        xl[row * 65 + fo + 2] = v.z;
        xl[row * 65 + fo + 3] = v.w;
    }
    __syncthreads();

    float xr[FF];
#pragma unroll
    for (int f = 0; f < FF; ++f) xr[f] = xl[t * 65 + f];

    const double bf = (double)bias[0];
    double sigd[KK], selv[KK];
#pragma unroll
    for (int k = 0; k < KK; ++k) {
        double s = (double)rbl[k];
#pragma unroll
        for (int f = 0; f < FF; ++f)
            s += (double)rwl[k * FF + f] * (double)xr[f];
        double sg = 1.0 / (1.0 + exp(-s));
        sigd[k] = sg;
        selv[k] = sg + bf;
    }

    int idx4[TOPKN];
#pragma unroll
    for (int tt = 0; tt < TOPKN; ++tt) {
        double m = -1e300; int mi = 0;
#pragma unroll
        for (int k = 0; k < KK; ++k) {
            if (selv[k] > m) { m = selv[k]; mi = k; }   // strict > : ties -> lowest idx
        }
        idx4[tt] = mi;
        selv[mi] = -1e300;
    }
    double ssum = 0.0;
#pragma unroll
    for (int tt = 0; tt < TOPKN; ++tt) ssum += sigd[idx4[tt]];

    float rv[KK];
#pragma unroll
    for (int k = 0; k < KK; ++k) rv[k] = 0.f;
#pragma unroll
    for (int tt = 0; tt < TOPKN; ++tt)
        rv[idx4[tt]] = (float)(sigd[idx4[tt]] / ssum);

    const long row = (long)blockIdx.x * 128 + t;
    float4* rdst = (float4*)(route + row * KK);
#pragma unroll
    for (int q = 0; q < 4; ++q)
        rdst[q] = make_float4(rv[q*4], rv[q*4+1], rv[q*4+2], rv[q*4+3]);

    float4 ti = make_float4((float)idx4[0], (float)idx4[1], (float)idx4[2], (float)idx4[3]);
    *(float4*)(topk_out + row * TOPKN) = ti;
}

// ---------------------------------------------------------------------------
// Kernel 2: softmax over G=32 of E1, times coef[e]  (coef folded here).
// grid 2048 x block 256 : 8 rows/block, 32 lanes/row.
// ---------------------------------------------------------------------------
__global__ __launch_bounds__(256)
void e1_softmax_kernel(const float* __restrict__ E1,
                       const float* __restrict__ lq1, const float* __restrict__ lk1,
                       const float* __restrict__ lq2, const float* __restrict__ lk2,
                       float* __restrict__ E1c)
{
    const int t = threadIdx.x;
    const long row = (long)blockIdx.x * 8 + (t >> 5);
    const int l = t & 31;
    float val = E1[row * GG + l];
    float m = val;
#pragma unroll
    for (int s = 16; s >= 1; s >>= 1) m = fmaxf(m, __shfl_xor(m, s, 32));
    float ex = expf(val - m);
    float sum = ex;
#pragma unroll
    for (int s = 16; s >= 1; s >>= 1) sum += __shfl_xor(sum, s, 32);
    float sm = ex / sum;

    const int e = (int)(row >> 13);   // row / (K*N)
    float coef = 1.0f;
    if (e) {
        float l1 = 0.f, l2 = 0.f;
#pragma unroll
        for (int i = 0; i < 64; ++i) {
            l1 = fmaf(lq1[i], lk1[i], l1);
            l2 = fmaf(lq2[i], lk2[i], l2);
        }
        const float lambda_init = 0.3555090675909692f;  // 0.8 - 0.6*exp(-0.3)
        coef = -(expf(l1) - expf(l2) + lambda_init);
    }
    E1c[row * GG + l] = coef * sm;
}

// ---------------------------------------------------------------------------
// Kernel 3: softmax over N=512 of E2. grid 1024 x block 256, 2 elems/thread.
// ---------------------------------------------------------------------------
__global__ __launch_bounds__(256)
void e2_softmax_kernel(const float* __restrict__ E2, float* __restrict__ E2s)
{
    __shared__ float red[4];
    const int t = threadIdx.x;
    const long base = (long)blockIdx.x * NN;
    float v0 = E2[base + t], v1 = E2[base + t + 256];
    float m = fmaxf(v0, v1);
#pragma unroll
    for (int s = 32; s >= 1; s >>= 1) m = fmaxf(m, __shfl_xor(m, s));
    if ((t & 63) == 0) red[t >> 6] = m;
    __syncthreads();
    m = fmaxf(fmaxf(red[0], red[1]), fmaxf(red[2], red[3]));
    float e0 = expf(v0 - m), e1 = expf(v1 - m);
    float s2 = e0 + e1;
#pragma unroll
    for (int s = 32; s >= 1; s >>= 1) s2 += __shfl_xor(s2, s);
    __syncthreads();
    if ((t & 63) == 0) red[t >> 6] = s2;
    __syncthreads();
    s2 = red[0] + red[1] + red[2] + red[3];
    E2s[base + t] = e0 / s2;
    E2s[base + t + 256] = e1 / s2;
}

// ---------------------------------------------------------------------------
// Kernel 4 (phase A): M[b,k,(e*32+d),f] = sum_j E2s[e,k,d,j]*x[b,j,f]
// grid 1024 = (b,k); block 256 = 4 waves; both e computed per block.
// Each lane owns an 8d x 8f fp32 register tile for one e; waves split j.
// ---------------------------------------------------------------------------
__global__ __launch_bounds__(256)
void phaseA_kernel(const float* __restrict__ x, const float* __restrict__ E2s,
                   float* __restrict__ M)
{
    __shared__ __align__(16) float smem[16384];  // [0..8191] xl[jj][f], [8192..] e2t[e][jj][d]
    const int t = threadIdx.x;
    const int b = blockIdx.x >> 4, k = blockIdx.x & 15;
    const int wid = t >> 6, lane = t & 63;
    const int e = lane >> 5, q = lane & 31;
    const int d0 = (q & 3) * 8, f0 = (q >> 2) * 8;

    float acc[64];
#pragma unroll
    for (int i = 0; i < 64; ++i) acc[i] = 0.f;

    const float* xb = x + (long)b * NN * FF;

    for (int tile = 0; tile < 4; ++tile) {
        const int j0 = tile * 128;
        // stage x tile: 8192 floats, linear
        {
            const float4* src = (const float4*)(xb + (long)j0 * FF);
            float4* dst = (float4*)smem;
#pragma unroll
            for (int qq = 0; qq < 8; ++qq) dst[t + qq * 256] = src[t + qq * 256];
        }
        // stage e2 transposed: e2t[e][jj][d]
        {
            const int ee = t >> 7;
            const int r = t & 127;
            const int d = r & 31;
            const int jr = (r >> 5) * 32;
            const float* s2 = E2s + ((long)(ee * KK + k) * GG + d) * NN + j0 + jr;
            float* dstp = smem + 8192 + (ee * 128 + jr) * 32 + d;
#pragma unroll
            for (int jj = 0; jj < 32; ++jj) dstp[jj * 32] = s2[jj];
        }
        __syncthreads();

        const int js = wid * 32;
        for (int jj = js; jj < js + 32; ++jj) {
            const float4 xa = *(const float4*)&smem[jj * 64 + f0];
            const float4 xb4 = *(const float4*)&smem[jj * 64 + f0 + 4];
            const float4 ea = *(const float4*)&smem[8192 + (e * 128 + jj) * 32 + d0];
            const float4 eb = *(const float4*)&smem[8192 + (e * 128 + jj) * 32 + d0 + 4];
            const float er[8] = {ea.x, ea.y, ea.z, ea.w, eb.x, eb.y, eb.z, eb.w};
            const float xr[8] = {xa.x, xa.y, xa.z, xa.w, xb4.x, xb4.y, xb4.z, xb4.w};
#pragma unroll
            for (int dd = 0; dd < 8; ++dd)
#pragma unroll
                for (int ff = 0; ff < 8; ++ff)
                    acc[dd * 8 + ff] = fmaf(er[dd], xr[ff], acc[dd * 8 + ff]);
        }
        __syncthreads();
    }

    // write per-wave partials to LDS in canonical order
#pragma unroll
    for (int dd = 0; dd < 8; ++dd)
#pragma unroll
        for (int ff = 0; ff < 8; ++ff)
            smem[wid * 4096 + e * 2048 + (d0 + dd) * 64 + (f0 + ff)] = acc[dd * 8 + ff];
    __syncthreads();

    // reduce 4 partials and store M (linear, coalesced)
    float* Mp = M + (long)blockIdx.x * 4096;
#pragma unroll
    for (int qq = 0; qq < 16; ++qq) {
        int o = t + qq * 256;
        Mp[o] = smem[o] + smem[o + 4096] + smem[o + 8192] + smem[o + 12288];
    }
}

// ---------------------------------------------------------------------------
// Kernel 5 (phase B): out[b,i,f] = sum_{k in top4(b,i)} w * sum_ed E1c*M
// grid 512 = (b, i-tile of 64); block 256. Per k: stage M2[b,k] (64x64) and
// E1c rows in LDS, compact the selected-row list, process rows 4-at-a-time.
// ---------------------------------------------------------------------------
__global__ __launch_bounds__(256)
void phaseB_kernel(const float* __restrict__ Mg, const float* __restrict__ E1c,
                   const float* __restrict__ route, float* __restrict__ out)
{
    __shared__ __align__(16) float Ml[4096];
    __shared__ __align__(16) float e1l[4096];
    __shared__ __align__(16) float outl[4096];
    __shared__ float rl[64];
    __shared__ int lst[64];
    __shared__ int cnt;

    const int t = threadIdx.x;
    const int b = blockIdx.x >> 3;
    const int i0 = (blockIdx.x & 7) * 64;
    const int wid = t >> 6, lane = t & 63;

#pragma unroll
    for (int qq = 0; qq < 16; ++qq) outl[t + qq * 256] = 0.f;
    __syncthreads();

    for (int k = 0; k < KK; ++k) {
        // stage M tile (4096 floats, linear)
        {
            const float4* src = (const float4*)(Mg + (long)(b * KK + k) * 4096);
            float4* dst = (float4*)Ml;
#pragma unroll
            for (int qq = 0; qq < 4; ++qq) dst[t + qq * 256] = src[t + qq * 256];
        }
        // stage E1c rows: e1l[r][ed], ed = e*32+d
        {
            const int r = t >> 2;
            const int ed0 = (t & 3) * 16;
            const int e = ed0 >> 5;
            const int dbase = ed0 & 31;
            const float4* src = (const float4*)(E1c + ((long)(e * KK + k) * NN + i0 + r) * GG + dbase);
            float4* dst = (float4*)(e1l + r * 64 + ed0);
#pragma unroll
            for (int qq = 0; qq < 4; ++qq) dst[qq] = src[qq];
        }
        if (t < 64) rl[t] = route[((long)b * NN + i0 + t) * KK + k];
        __syncthreads();

        if (t < 64) {
            bool act = (rl[t] != 0.f);
            unsigned long long mask = __ballot(act);
            if (act) {
                int rank = __popcll(mask & ((1ull << t) - 1ull));
                lst[rank] = t;
            }
            if (t == 0) cnt = (int)__popcll(mask);
        }
        __syncthreads();

        const int C = cnt;
        const int ngrp = (C + 3) >> 2;
        for (int g = wid; g < ngrp; g += 4) {
            const int li = g * 4 + (lane >> 4);
            const int fq = lane & 15;
            const int lic = (li < C) ? li : (C - 1);
            const int r = lst[lic];
            const float w = (li < C) ? rl[r] : 0.f;
            float4 a = make_float4(0.f, 0.f, 0.f, 0.f);
#pragma unroll
            for (int ed = 0; ed < 64; ++ed) {
                const float ev = e1l[r * 64 + ed];
                const float4 m4 = *(const float4*)&Ml[ed * 64 + fq * 4];
                a.x = fmaf(ev, m4.x, a.x);
                a.y = fmaf(ev, m4.y, a.y);
                a.z = fmaf(ev, m4.z, a.z);
                a.w = fmaf(ev, m4.w, a.w);
            }
            if (li < C) {
                float* o = &outl[r * 64 + fq * 4];
                o[0] += w * a.x; o[1] += w * a.y; o[2] += w * a.z; o[3] += w * a.w;
            }
        }
        __syncthreads();
    }

    float* og = out + ((long)b * NN + i0) * FF;
#pragma unroll
    for (int qq = 0; qq < 16; ++qq) og[t + qq * 256] = outl[t + qq * 256];
}

// ---------------------------------------------------------------------------
extern "C" void kernel_launch(void* const* d_in, const int* in_sizes, int n_in,
                              void* d_out, int out_size, void* d_ws, size_t ws_size,
                              hipStream_t stream)
{
    const float* x   = (const float*)d_in[0];
    const float* E1  = (const float*)d_in[1];
    const float* E2  = (const float*)d_in[2];
    const float* rw  = (const float*)d_in[3];
    const float* rb  = (const float*)d_in[4];
    // d_in[5] = outer_lambda: algebraically unused (outer == identity)
    const float* lq1 = (const float*)d_in[6];
    const float* lk1 = (const float*)d_in[7];
    const float* lq2 = (const float*)d_in[8];
    const float* lk2 = (const float*)d_in[9];
    const int*  bias = (const int*)d_in[10];

    float* ws    = (float*)d_ws;
    float* route = ws + ROUTE_OFF;
    float* E1c   = ws + E1C_OFF;
    float* E2s   = ws + E2S_OFF;
    float* M     = ws + M_OFF;

    float* out      = (float*)d_out;
    float* topk_out = out + (long)BB * NN * FF;

    hipLaunchKernelGGL(router_kernel, dim3(256), dim3(128), 0, stream,
                       x, rw, rb, bias, route, topk_out);
    hipLaunchKernelGGL(e1_softmax_kernel, dim3(2048), dim3(256), 0, stream,
                       E1, lq1, lk1, lq2, lk2, E1c);
    hipLaunchKernelGGL(e2_softmax_kernel, dim3(1024), dim3(256), 0, stream,
                       E2, E2s);
    hipLaunchKernelGGL(phaseA_kernel, dim3(1024), dim3(256), 0, stream,
                       x, E2s, M);
    hipLaunchKernelGGL(phaseB_kernel, dim3(512), dim3(256), 0, stream,
                       M, E1c, route, out);
}

// Round 2
// 109.682 us; speedup vs baseline: 1.3044x; 1.3044x over previous
//
#include <hip/hip_runtime.h>
#include <hip/hip_bf16.h>

#define BB 64
#define NN 512
#define FF 64
#define KK 16
#define GG 32
#define TOPKN 4

typedef __attribute__((ext_vector_type(8))) __bf16 bf16x8;
typedef __attribute__((ext_vector_type(4))) float f32x4;

// workspace layout (float offsets)
#define ROUTE_OFF 0                              // B*N*K           = 524288 f
#define E1C_OFF   (BB*NN*KK)                     // 2*K*N*G         = 524288 f
#define E2SB_OFF  (E1C_OFF + 2*KK*NN*GG)         // bf16 1024x512   = 262144 f
#define XT_OFF    (E2SB_OFF + (2*KK*GG*NN)/2)    // bf16 64x64x512  = 1048576 f
#define M_OFF     (XT_OFF + (BB*FF*NN)/2)        // B*K*64*F fp32   = 4194304 f
// total ws floats = 6553600 (~26.2 MB)

// ---------------------------------------------------------------------------
// Kernel 1: router (fp64 accumulate for exact top-k ordering)
// ---------------------------------------------------------------------------
__global__ __launch_bounds__(128)
void router_kernel(const float* __restrict__ x, const float* __restrict__ rw,
                   const float* __restrict__ rb, const int* __restrict__ bias,
                   float* __restrict__ route, float* __restrict__ topk_out)
{
    __shared__ float rwl[KK * FF];
    __shared__ float rbl[KK];
    __shared__ float xl[128 * 65];

    const int t = threadIdx.x;
    for (int i = t; i < KK * FF; i += 128) rwl[i] = rw[i];
    if (t < KK) rbl[t] = rb[t];

    const long base = (long)blockIdx.x * 128 * FF;
    const float4* src = (const float4*)(x + base);
    for (int q = 0; q < 16; ++q) {
        int idx = t + q * 128;
        float4 v = src[idx];
        int row = idx >> 4;
        int fo = (idx & 15) * 4;
        xl[row * 65 + fo + 0] = v.x;
        xl[row * 65 + fo + 1] = v.y;
        xl[row * 65 + fo + 2] = v.z;
        xl[row * 65 + fo + 3] = v.w;
    }
    __syncthreads();

    float xr[FF];
#pragma unroll
    for (int f = 0; f < FF; ++f) xr[f] = xl[t * 65 + f];

    const double bf = (double)bias[0];
    double sigd[KK], selv[KK];
#pragma unroll
    for (int k = 0; k < KK; ++k) {
        double s = (double)rbl[k];
#pragma unroll
        for (int f = 0; f < FF; ++f)
            s += (double)rwl[k * FF + f] * (double)xr[f];
        double sg = 1.0 / (1.0 + exp(-s));
        sigd[k] = sg;
        selv[k] = sg + bf;
    }

    int idx4[TOPKN];
#pragma unroll
    for (int tt = 0; tt < TOPKN; ++tt) {
        double m = -1e300; int mi = 0;
#pragma unroll
        for (int k = 0; k < KK; ++k) {
            if (selv[k] > m) { m = selv[k]; mi = k; }
        }
        idx4[tt] = mi;
        selv[mi] = -1e300;
    }
    double ssum = 0.0;
#pragma unroll
    for (int tt = 0; tt < TOPKN; ++tt) ssum += sigd[idx4[tt]];

    float rv[KK];
#pragma unroll
    for (int k = 0; k < KK; ++k) rv[k] = 0.f;
#pragma unroll
    for (int tt = 0; tt < TOPKN; ++tt)
        rv[idx4[tt]] = (float)(sigd[idx4[tt]] / ssum);

    const long row = (long)blockIdx.x * 128 + t;
    float4* rdst = (float4*)(route + row * KK);
#pragma unroll
    for (int q = 0; q < 4; ++q)
        rdst[q] = make_float4(rv[q*4], rv[q*4+1], rv[q*4+2], rv[q*4+3]);

    float4 ti = make_float4((float)idx4[0], (float)idx4[1], (float)idx4[2], (float)idx4[3]);
    *(float4*)(topk_out + row * TOPKN) = ti;
}

// ---------------------------------------------------------------------------
// Kernel 2: E1 softmax over G, times coef[e]
// ---------------------------------------------------------------------------
__global__ __launch_bounds__(256)
void e1_softmax_kernel(const float* __restrict__ E1,
                       const float* __restrict__ lq1, const float* __restrict__ lk1,
                       const float* __restrict__ lq2, const float* __restrict__ lk2,
                       float* __restrict__ E1c)
{
    const int t = threadIdx.x;
    const long row = (long)blockIdx.x * 8 + (t >> 5);
    const int l = t & 31;
    float val = E1[row * GG + l];
    float m = val;
#pragma unroll
    for (int s = 16; s >= 1; s >>= 1) m = fmaxf(m, __shfl_xor(m, s, 32));
    float ex = expf(val - m);
    float sum = ex;
#pragma unroll
    for (int s = 16; s >= 1; s >>= 1) sum += __shfl_xor(sum, s, 32);
    float sm = ex / sum;

    const int e = (int)(row >> 13);
    float coef = 1.0f;
    if (e) {
        float l1 = 0.f, l2 = 0.f;
#pragma unroll
        for (int i = 0; i < 64; ++i) {
            l1 = fmaf(lq1[i], lk1[i], l1);
            l2 = fmaf(lq2[i], lk2[i], l2);
        }
        const float lambda_init = 0.3555090675909692f;
        coef = -(expf(l1) - expf(l2) + lambda_init);
    }
    E1c[row * GG + l] = coef * sm;
}

// ---------------------------------------------------------------------------
// Kernel 3: E2 softmax over N=512, bf16 output (MFMA A-operand layout:
// row = (e*16+k)*32+d, j contiguous)
// ---------------------------------------------------------------------------
__global__ __launch_bounds__(256)
void e2_softmax_kernel(const float* __restrict__ E2, __hip_bfloat16* __restrict__ E2sb)
{
    __shared__ float red[4];
    const int t = threadIdx.x;
    const long base = (long)blockIdx.x * NN;
    float v0 = E2[base + t], v1 = E2[base + t + 256];
    float m = fmaxf(v0, v1);
#pragma unroll
    for (int s = 32; s >= 1; s >>= 1) m = fmaxf(m, __shfl_xor(m, s));
    if ((t & 63) == 0) red[t >> 6] = m;
    __syncthreads();
    m = fmaxf(fmaxf(red[0], red[1]), fmaxf(red[2], red[3]));
    float e0 = expf(v0 - m), e1 = expf(v1 - m);
    float s2 = e0 + e1;
#pragma unroll
    for (int s = 32; s >= 1; s >>= 1) s2 += __shfl_xor(s2, s);
    __syncthreads();
    if ((t & 63) == 0) red[t >> 6] = s2;
    __syncthreads();
    s2 = red[0] + red[1] + red[2] + red[3];
    E2sb[base + t] = __float2bfloat16(e0 / s2);
    E2sb[base + t + 256] = __float2bfloat16(e1 / s2);
}

// ---------------------------------------------------------------------------
// Kernel 3b: x transpose to bf16: xT[b][f][j]  (MFMA B-operand, K=j contiguous)
// ---------------------------------------------------------------------------
__global__ __launch_bounds__(256)
void xpose_kernel(const float* __restrict__ x, __hip_bfloat16* __restrict__ xT)
{
    __shared__ float xl[64 * 65];
    const int t = threadIdx.x;
    const int b = blockIdx.x;
    const float* xb = x + (long)b * NN * FF;
    __hip_bfloat16* xo = xT + (long)b * FF * NN;
    for (int c = 0; c < 8; ++c) {
        const int j0 = c * 64;
        const float4* src = (const float4*)(xb + (long)j0 * FF);
#pragma unroll
        for (int q = 0; q < 4; ++q) {
            int idx = t + q * 256;
            float4 v = src[idx];
            int j = idx >> 4;
            int f = (idx & 15) * 4;
            xl[j * 65 + f + 0] = v.x;
            xl[j * 65 + f + 1] = v.y;
            xl[j * 65 + f + 2] = v.z;
            xl[j * 65 + f + 3] = v.w;
        }
        __syncthreads();
#pragma unroll
        for (int q = 0; q < 16; ++q) {
            int idx = t + q * 256;
            int f = idx >> 6, j = idx & 63;
            xo[(long)f * NN + j0 + j] = __float2bfloat16(xl[j * 65 + f]);
        }
        __syncthreads();
    }
}

// ---------------------------------------------------------------------------
// Kernel 4 (phase A, MFMA): per (b,k): M[64ed x 64f] = E2row[64x512] . xT[64x512]^T
// 4 waves, wave w owns ed rows [16w,16w+16). BK=128 (256B rows), XOR-swizzled
// LDS via pre-swizzled global source for global_load_lds (rule #21).
// ---------------------------------------------------------------------------
__global__ __launch_bounds__(256)
void phaseA_mfma(const __hip_bfloat16* __restrict__ E2sb,
                 const __hip_bfloat16* __restrict__ xT,
                 float* __restrict__ M)
{
    __shared__ __align__(16) char smem[32768];  // A tile 16KB | B tile 16KB
    const int t = threadIdx.x;
    const int b = blockIdx.x >> 4, k = blockIdx.x & 15;
    const int wid = t >> 6, lane = t & 63;
    const int lo = lane & 15, hi = lane >> 4;

    const char* e2p = (const char*)E2sb;
    const char* xp  = (const char*)(xT + (long)b * FF * NN);

    f32x4 acc[4] = {};

    for (int tile = 0; tile < 4; ++tile) {
        const int j0b = tile * 256;   // byte offset into the 1024B global row
#pragma unroll
        for (int q = 0; q < 4; ++q) {
            const int Lb = (wid * 4 + q) * 1024 + lane * 16;  // LDS byte (linear dest)
            const int ed = Lb >> 8;                            // tile row (256B rows)
            const int jb = (Lb & 255) ^ ((ed & 7) << 4);       // inverse-swizzled col
            const int rowA = ((ed >> 5) * 512) + k * 32 + (ed & 31);
            __builtin_amdgcn_global_load_lds(
                (const __attribute__((address_space(1))) void*)(e2p + (long)rowA * 1024 + j0b + jb),
                (__attribute__((address_space(3))) void*)(smem + (wid * 4 + q) * 1024),
                16, 0, 0);
            __builtin_amdgcn_global_load_lds(
                (const __attribute__((address_space(1))) void*)(xp + (long)ed * 1024 + j0b + jb),
                (__attribute__((address_space(3))) void*)(smem + 16384 + (wid * 4 + q) * 1024),
                16, 0, 0);
        }
        __syncthreads();

#pragma unroll
        for (int ks = 0; ks < 4; ++ks) {
            const int cb = ks * 64 + hi * 16;        // K-byte offset in row
            const int arow = wid * 16 + lo;
            const int abyte = arow * 256 + (cb ^ ((arow & 7) << 4));
            bf16x8 a = *(const bf16x8*)(smem + abyte);
#pragma unroll
            for (int nf = 0; nf < 4; ++nf) {
                const int brow = nf * 16 + lo;
                const int bbyte = 16384 + brow * 256 + (cb ^ ((brow & 7) << 4));
                bf16x8 bv = *(const bf16x8*)(smem + bbyte);
                acc[nf] = __builtin_amdgcn_mfma_f32_16x16x32_bf16(a, bv, acc[nf], 0, 0, 0);
            }
        }
        __syncthreads();
    }

    // C/D mapping: col = lane&15 (f), row = (lane>>4)*4 + reg (ed within wave slice)
    float* Mp = M + (long)blockIdx.x * 4096;
#pragma unroll
    for (int nf = 0; nf < 4; ++nf) {
#pragma unroll
        for (int r = 0; r < 4; ++r) {
            const int m = wid * 16 + hi * 4 + r;
            const int f = nf * 16 + lo;
            Mp[m * 64 + f] = acc[nf][r];
        }
    }
}

// ---------------------------------------------------------------------------
// Kernel 5 (phase B): unchanged fp32 sparse contraction
// ---------------------------------------------------------------------------
__global__ __launch_bounds__(256)
void phaseB_kernel(const float* __restrict__ Mg, const float* __restrict__ E1c,
                   const float* __restrict__ route, float* __restrict__ out)
{
    __shared__ __align__(16) float Ml[4096];
    __shared__ __align__(16) float e1l[4096];
    __shared__ __align__(16) float outl[4096];
    __shared__ float rl[64];
    __shared__ int lst[64];
    __shared__ int cnt;

    const int t = threadIdx.x;
    const int b = blockIdx.x >> 3;
    const int i0 = (blockIdx.x & 7) * 64;
    const int wid = t >> 6, lane = t & 63;

#pragma unroll
    for (int qq = 0; qq < 16; ++qq) outl[t + qq * 256] = 0.f;
    __syncthreads();

    for (int k = 0; k < KK; ++k) {
        {
            const float4* src = (const float4*)(Mg + (long)(b * KK + k) * 4096);
            float4* dst = (float4*)Ml;
#pragma unroll
            for (int qq = 0; qq < 4; ++qq) dst[t + qq * 256] = src[t + qq * 256];
        }
        {
            const int r = t >> 2;
            const int ed0 = (t & 3) * 16;
            const int e = ed0 >> 5;
            const int dbase = ed0 & 31;
            const float4* src = (const float4*)(E1c + ((long)(e * KK + k) * NN + i0 + r) * GG + dbase);
            float4* dst = (float4*)(e1l + r * 64 + ed0);
#pragma unroll
            for (int qq = 0; qq < 4; ++qq) dst[qq] = src[qq];
        }
        if (t < 64) rl[t] = route[((long)b * NN + i0 + t) * KK + k];
        __syncthreads();

        if (t < 64) {
            bool act = (rl[t] != 0.f);
            unsigned long long mask = __ballot(act);
            if (act) {
                int rank = __popcll(mask & ((1ull << t) - 1ull));
                lst[rank] = t;
            }
            if (t == 0) cnt = (int)__popcll(mask);
        }
        __syncthreads();

        const int C = cnt;
        const int ngrp = (C + 3) >> 2;
        for (int g = wid; g < ngrp; g += 4) {
            const int li = g * 4 + (lane >> 4);
            const int fq = lane & 15;
            const int lic = (li < C) ? li : (C - 1);
            const int r = lst[lic];
            const float w = (li < C) ? rl[r] : 0.f;
            float4 a = make_float4(0.f, 0.f, 0.f, 0.f);
#pragma unroll
            for (int ed = 0; ed < 64; ++ed) {
                const float ev = e1l[r * 64 + ed];
                const float4 m4 = *(const float4*)&Ml[ed * 64 + fq * 4];
                a.x = fmaf(ev, m4.x, a.x);
                a.y = fmaf(ev, m4.y, a.y);
                a.z = fmaf(ev, m4.z, a.z);
                a.w = fmaf(ev, m4.w, a.w);
            }
            if (li < C) {
                float* o = &outl[r * 64 + fq * 4];
                o[0] += w * a.x; o[1] += w * a.y; o[2] += w * a.z; o[3] += w * a.w;
            }
        }
        __syncthreads();
    }

    float* og = out + ((long)b * NN + i0) * FF;
#pragma unroll
    for (int qq = 0; qq < 16; ++qq) og[t + qq * 256] = outl[t + qq * 256];
}

// ---------------------------------------------------------------------------
extern "C" void kernel_launch(void* const* d_in, const int* in_sizes, int n_in,
                              void* d_out, int out_size, void* d_ws, size_t ws_size,
                              hipStream_t stream)
{
    const float* x   = (const float*)d_in[0];
    const float* E1  = (const float*)d_in[1];
    const float* E2  = (const float*)d_in[2];
    const float* rw  = (const float*)d_in[3];
    const float* rb  = (const float*)d_in[4];
    // d_in[5] = outer_lambda: algebraically unused (outer == identity)
    const float* lq1 = (const float*)d_in[6];
    const float* lk1 = (const float*)d_in[7];
    const float* lq2 = (const float*)d_in[8];
    const float* lk2 = (const float*)d_in[9];
    const int*  bias = (const int*)d_in[10];

    float* ws    = (float*)d_ws;
    float* route = ws + ROUTE_OFF;
    float* E1c   = ws + E1C_OFF;
    __hip_bfloat16* E2sb = (__hip_bfloat16*)(ws + E2SB_OFF);
    __hip_bfloat16* xT   = (__hip_bfloat16*)(ws + XT_OFF);
    float* M     = ws + M_OFF;

    float* out      = (float*)d_out;
    float* topk_out = out + (long)BB * NN * FF;

    hipLaunchKernelGGL(router_kernel, dim3(256), dim3(128), 0, stream,
                       x, rw, rb, bias, route, topk_out);
    hipLaunchKernelGGL(e1_softmax_kernel, dim3(2048), dim3(256), 0, stream,
                       E1, lq1, lk1, lq2, lk2, E1c);
    hipLaunchKernelGGL(e2_softmax_kernel, dim3(1024), dim3(256), 0, stream,
                       E2, E2sb);
    hipLaunchKernelGGL(xpose_kernel, dim3(64), dim3(256), 0, stream,
                       x, xT);
    hipLaunchKernelGGL(phaseA_mfma, dim3(1024), dim3(256), 0, stream,
                       E2sb, xT, M);
    hipLaunchKernelGGL(phaseB_kernel, dim3(512), dim3(256), 0, stream,
                       M, E1c, route, out);
}

// Round 4
// 68.023 us; speedup vs baseline: 2.1033x; 1.6124x over previous
//
#include <hip/hip_runtime.h>
#include <hip/hip_bf16.h>

#define BB 64
#define NN 512
#define FF 64
#define KK 16
#define GG 32
#define TOPKN 4

typedef __attribute__((ext_vector_type(8))) __bf16 bf16x8;
typedef __attribute__((ext_vector_type(4))) float f32x4;

// workspace layout (float offsets)
#define ROUTET_OFF 0                               // fp32 [b][k][i]  = 524288 f
#define E1CB_OFF   (BB*KK*NN)                      // bf16 [e,k,i,d]  = 262144 f
#define E2SB_OFF   (E1CB_OFF + (2*KK*NN*GG)/2)     // bf16 1024x512   = 262144 f
#define XT_OFF     (E2SB_OFF + (2*KK*GG*NN)/2)     // bf16 [b][f][j]  = 1048576 f
#define MT_OFF     (XT_OFF + (BB*FF*NN)/2)         // bf16 [b][f][ked]= 2097152 f
// total ws floats = 4194304 (~16.8 MB)

// ---------------------------------------------------------------------------
// Kernel 1: router (fp64 accumulate for exact top-k ordering)
// writes routeT[b][k][i] (transposed, coalesced per-k) + topk indices
// ---------------------------------------------------------------------------
__global__ __launch_bounds__(128)
void router_kernel(const float* __restrict__ x, const float* __restrict__ rw,
                   const float* __restrict__ rb, const int* __restrict__ bias,
                   float* __restrict__ routeT, float* __restrict__ topk_out)
{
    __shared__ float rwl[KK * FF];
    __shared__ float rbl[KK];
    __shared__ float xl[128 * 65];

    const int t = threadIdx.x;
    for (int i = t; i < KK * FF; i += 128) rwl[i] = rw[i];
    if (t < KK) rbl[t] = rb[t];

    const long base = (long)blockIdx.x * 128 * FF;
    const float4* src = (const float4*)(x + base);
    for (int q = 0; q < 16; ++q) {
        int idx = t + q * 128;
        float4 v = src[idx];
        int row = idx >> 4;
        int fo = (idx & 15) * 4;
        xl[row * 65 + fo + 0] = v.x;
        xl[row * 65 + fo + 1] = v.y;
        xl[row * 65 + fo + 2] = v.z;
        xl[row * 65 + fo + 3] = v.w;
    }
    __syncthreads();

    float xr[FF];
#pragma unroll
    for (int f = 0; f < FF; ++f) xr[f] = xl[t * 65 + f];

    const double bf = (double)bias[0];
    double sigd[KK], selv[KK];
#pragma unroll
    for (int k = 0; k < KK; ++k) {
        double s = (double)rbl[k];
#pragma unroll
        for (int f = 0; f < FF; ++f)
            s += (double)rwl[k * FF + f] * (double)xr[f];
        double sg = 1.0 / (1.0 + exp(-s));
        sigd[k] = sg;
        selv[k] = sg + bf;
    }

    int idx4[TOPKN];
#pragma unroll
    for (int tt = 0; tt < TOPKN; ++tt) {
        double m = -1e300; int mi = 0;
#pragma unroll
        for (int k = 0; k < KK; ++k) {
            if (selv[k] > m) { m = selv[k]; mi = k; }
        }
        idx4[tt] = mi;
        selv[mi] = -1e300;
    }
    double ssum = 0.0;
#pragma unroll
    for (int tt = 0; tt < TOPKN; ++tt) ssum += sigd[idx4[tt]];

    float rv[KK];
#pragma unroll
    for (int k = 0; k < KK; ++k) rv[k] = 0.f;
#pragma unroll
    for (int tt = 0; tt < TOPKN; ++tt)
        rv[idx4[tt]] = (float)(sigd[idx4[tt]] / ssum);

    const long row = (long)blockIdx.x * 128 + t;
    const int b = (int)(row >> 9);
    const int n = (int)(row & 511);
#pragma unroll
    for (int k = 0; k < KK; ++k)
        routeT[((long)b * KK + k) * NN + n] = rv[k];

    float4 ti = make_float4((float)idx4[0], (float)idx4[1], (float)idx4[2], (float)idx4[3]);
    *(float4*)(topk_out + row * TOPKN) = ti;
}

// ---------------------------------------------------------------------------
// Kernel 2: E1 softmax over G, times coef[e], bf16 output [e,k,i,d]
// ---------------------------------------------------------------------------
__global__ __launch_bounds__(256)
void e1_softmax_kernel(const float* __restrict__ E1,
                       const float* __restrict__ lq1, const float* __restrict__ lk1,
                       const float* __restrict__ lq2, const float* __restrict__ lk2,
                       __hip_bfloat16* __restrict__ E1cb)
{
    const int t = threadIdx.x;
    const long row = (long)blockIdx.x * 8 + (t >> 5);
    const int l = t & 31;
    float val = E1[row * GG + l];
    float m = val;
#pragma unroll
    for (int s = 16; s >= 1; s >>= 1) m = fmaxf(m, __shfl_xor(m, s, 32));
    float ex = expf(val - m);
    float sum = ex;
#pragma unroll
    for (int s = 16; s >= 1; s >>= 1) sum += __shfl_xor(sum, s, 32);
    float sm = ex / sum;

    const int e = (int)(row >> 13);
    float coef = 1.0f;
    if (e) {
        float l1 = 0.f, l2 = 0.f;
#pragma unroll
        for (int i = 0; i < 64; ++i) {
            l1 = fmaf(lq1[i], lk1[i], l1);
            l2 = fmaf(lq2[i], lk2[i], l2);
        }
        const float lambda_init = 0.3555090675909692f;
        coef = -(expf(l1) - expf(l2) + lambda_init);
    }
    E1cb[row * GG + l] = __float2bfloat16(coef * sm);
}

// ---------------------------------------------------------------------------
// Kernel 3: E2 softmax over N=512, bf16 output rows (e*16+k)*32+d
// ---------------------------------------------------------------------------
__global__ __launch_bounds__(256)
void e2_softmax_kernel(const float* __restrict__ E2, __hip_bfloat16* __restrict__ E2sb)
{
    __shared__ float red[4];
    const int t = threadIdx.x;
    const long base = (long)blockIdx.x * NN;
    float v0 = E2[base + t], v1 = E2[base + t + 256];
    float m = fmaxf(v0, v1);
#pragma unroll
    for (int s = 32; s >= 1; s >>= 1) m = fmaxf(m, __shfl_xor(m, s));
    if ((t & 63) == 0) red[t >> 6] = m;
    __syncthreads();
    m = fmaxf(fmaxf(red[0], red[1]), fmaxf(red[2], red[3]));
    float e0 = expf(v0 - m), e1 = expf(v1 - m);
    float s2 = e0 + e1;
#pragma unroll
    for (int s = 32; s >= 1; s >>= 1) s2 += __shfl_xor(s2, s);
    __syncthreads();
    if ((t & 63) == 0) red[t >> 6] = s2;
    __syncthreads();
    s2 = red[0] + red[1] + red[2] + red[3];
    E2sb[base + t] = __float2bfloat16(e0 / s2);
    E2sb[base + t + 256] = __float2bfloat16(e1 / s2);
}

// ---------------------------------------------------------------------------
// Kernel 3b: x transpose to bf16: xT[b][f][j]
// ---------------------------------------------------------------------------
__global__ __launch_bounds__(256)
void xpose_kernel(const float* __restrict__ x, __hip_bfloat16* __restrict__ xT)
{
    __shared__ float xl[64 * 65];
    const int t = threadIdx.x;
    const int b = blockIdx.x;
    const float* xb = x + (long)b * NN * FF;
    __hip_bfloat16* xo = xT + (long)b * FF * NN;
    for (int c = 0; c < 8; ++c) {
        const int j0 = c * 64;
        const float4* src = (const float4*)(xb + (long)j0 * FF);
#pragma unroll
        for (int q = 0; q < 4; ++q) {
            int idx = t + q * 256;
            float4 v = src[idx];
            int j = idx >> 4;
            int f = (idx & 15) * 4;
            xl[j * 65 + f + 0] = v.x;
            xl[j * 65 + f + 1] = v.y;
            xl[j * 65 + f + 2] = v.z;
            xl[j * 65 + f + 3] = v.w;
        }
        __syncthreads();
#pragma unroll
        for (int q = 0; q < 16; ++q) {
            int idx = t + q * 256;
            int f = idx >> 6, j = idx & 63;
            xo[(long)f * NN + j0 + j] = __float2bfloat16(xl[j * 65 + f]);
        }
        __syncthreads();
    }
}

// ---------------------------------------------------------------------------
// Kernel 4 (phase A, MFMA): per (b,k): tile[64ed x 64f] = E2row . xT^T
// epilogue: padded-LDS transpose -> Mt bf16 [b][f][k*64+ed]
// ---------------------------------------------------------------------------
__global__ __launch_bounds__(256)
void phaseA_mfma(const __hip_bfloat16* __restrict__ E2sb,
                 const __hip_bfloat16* __restrict__ xT,
                 __hip_bfloat16* __restrict__ Mt)
{
    __shared__ __align__(16) char smem[32768];  // A tile 16KB | B tile 16KB
    const int t = threadIdx.x;
    // XCD swizzle: blocks sharing b land on the same XCD
    const int L = blockIdx.x;
    const int xc = L & 7, q = L >> 3;           // q in [0,128)
    const int b = xc * 8 + (q >> 4), k = q & 15;
    const int wid = t >> 6, lane = t & 63;
    const int lo = lane & 15, hi = lane >> 4;

    const char* e2p = (const char*)E2sb;
    const char* xp  = (const char*)(xT + (long)b * FF * NN);

    f32x4 acc[4] = {};

    for (int tile = 0; tile < 4; ++tile) {
        const int j0b = tile * 256;   // byte offset into the 1024B global row
#pragma unroll
        for (int qq = 0; qq < 4; ++qq) {
            const int Lb = (wid * 4 + qq) * 1024 + lane * 16;  // linear LDS byte
            const int ed = Lb >> 8;                            // 256B rows
            const int jb = (Lb & 255) ^ ((ed & 7) << 4);       // inverse-swizzled col
            const int rowA = ((ed >> 5) * 512) + k * 32 + (ed & 31);
            __builtin_amdgcn_global_load_lds(
                (const __attribute__((address_space(1))) void*)(e2p + (long)rowA * 1024 + j0b + jb),
                (__attribute__((address_space(3))) void*)(smem + (wid * 4 + qq) * 1024),
                16, 0, 0);
            __builtin_amdgcn_global_load_lds(
                (const __attribute__((address_space(1))) void*)(xp + (long)ed * 1024 + j0b + jb),
                (__attribute__((address_space(3))) void*)(smem + 16384 + (wid * 4 + qq) * 1024),
                16, 0, 0);
        }
        __syncthreads();

#pragma unroll
        for (int ks = 0; ks < 4; ++ks) {
            const int cb = ks * 64 + hi * 16;
            const int arow = wid * 16 + lo;
            const int abyte = arow * 256 + (cb ^ ((arow & 7) << 4));
            bf16x8 a = *(const bf16x8*)(smem + abyte);
#pragma unroll
            for (int nf = 0; nf < 4; ++nf) {
                const int brow = nf * 16 + lo;
                const int bbyte = 16384 + brow * 256 + (cb ^ ((brow & 7) << 4));
                bf16x8 bv = *(const bf16x8*)(smem + bbyte);
                acc[nf] = __builtin_amdgcn_mfma_f32_16x16x32_bf16(a, bv, acc[nf], 0, 0, 0);
            }
        }
        __syncthreads();
    }

    // transpose via padded LDS tile [64 m][65] fp32, then bf16 write to Mt
    float* tl = (float*)smem;
#pragma unroll
    for (int nf = 0; nf < 4; ++nf)
#pragma unroll
        for (int r = 0; r < 4; ++r)
            tl[(wid * 16 + hi * 4 + r) * 65 + nf * 16 + lo] = acc[nf][r];
    __syncthreads();

    const int f = t >> 2;
    const int m0 = (t & 3) * 16;
    bf16x8 a0, a1;
#pragma unroll
    for (int j = 0; j < 8; ++j) {
        a0[j] = (__bf16)tl[(m0 + j) * 65 + f];
        a1[j] = (__bf16)tl[(m0 + 8 + j) * 65 + f];
    }
    __hip_bfloat16* dst = Mt + (long)b * 65536 + (long)f * 1024 + k * 64 + m0;
    *(bf16x8*)dst = a0;
    *(bf16x8*)(dst + 8) = a1;
}

// ---------------------------------------------------------------------------
// Kernel 5 (phase B, MFMA): per b: out[512 x 64] = W[512 x 1024] @ Mt^T
// W constructed on the fly in registers: A-frag = E1cb segment * route weight.
// Staging fixed: global_load_lds with wave-uniform LDS base + lane*16 only.
// ---------------------------------------------------------------------------
__global__ __launch_bounds__(256)
void phaseB_mfma(const __hip_bfloat16* __restrict__ Mt,
                 const __hip_bfloat16* __restrict__ E1cb,
                 const float* __restrict__ routeT,
                 float* __restrict__ out)
{
    __shared__ __align__(16) char smem[8192];   // Mt slice [64 f][128B] swizzled
    const int t = threadIdx.x;
    // XCD swizzle: 8 i-tiles of one b on the same XCD
    const int L = blockIdx.x;
    const int xc = L & 7, q = L >> 3;           // q in [0,64)
    const int b = xc * 8 + (q >> 3);
    const int i0 = (q & 7) * 64;
    const int wid = t >> 6, lane = t & 63;
    const int lo = lane & 15, hi = lane >> 4;
    const int irow = i0 + wid * 16 + lo;        // this lane's output row

    // preload the 16 route weights for this row
    float wk[KK];
    const float* rT = routeT + (long)b * KK * NN + irow;
#pragma unroll
    for (int k = 0; k < KK; ++k) wk[k] = rT[k * NN];

    const char* mtp = (const char*)(Mt + (long)b * 65536);
    f32x4 acc[4] = {};

    for (int kk = 0; kk < KK; ++kk) {
        // stage Mt k-slice: 64 f rows x 128B. Wave-uniform LDS base, lane*16
        // within-chunk (HW rule); both-sides XOR swizzle via global source.
#pragma unroll
        for (int h = 0; h < 2; ++h) {
            const int cbase = wid * 2048 + h * 1024;     // wave-uniform LDS base
            const int Lb = cbase + lane * 16;            // linear LDS byte
            const int fr = Lb >> 7;                      // f row (128B rows)
            const int cb = (Lb & 127) ^ ((fr & 7) << 4); // inverse-swizzled col
            __builtin_amdgcn_global_load_lds(
                (const __attribute__((address_space(1))) void*)(mtp + (long)fr * 2048 + kk * 128 + cb),
                (__attribute__((address_space(3))) void*)(smem + cbase), 16, 0, 0);
        }
        // A-frags from global (coalesced 1KB/wave-instr), scaled by route wt
        bf16x8 afr[2];
#pragma unroll
        for (int ks = 0; ks < 2; ++ks) {
            const long off = ((long)(ks * KK + kk) * NN + irow) * GG + hi * 8;
            bf16x8 v = *(const bf16x8*)(E1cb + off);
            bf16x8 r;
#pragma unroll
            for (int j = 0; j < 8; ++j)
                r[j] = (__bf16)(wk[kk] * (float)v[j]);
            afr[ks] = r;
        }
        __syncthreads();
#pragma unroll
        for (int ks = 0; ks < 2; ++ks) {
#pragma unroll
            for (int nf = 0; nf < 4; ++nf) {
                const int frow = nf * 16 + lo;
                const int cb2 = (ks * 64 + hi * 16) ^ ((frow & 7) << 4);
                bf16x8 bv = *(const bf16x8*)(smem + frow * 128 + cb2);
                acc[nf] = __builtin_amdgcn_mfma_f32_16x16x32_bf16(afr[ks], bv, acc[nf], 0, 0, 0);
            }
        }
        __syncthreads();
    }

    // D: row = hi*4+r within the wave's 16-row tile, col f = nf*16+lo
    float* og = out + ((long)b * NN + i0 + wid * 16) * FF;
#pragma unroll
    for (int nf = 0; nf < 4; ++nf)
#pragma unroll
        for (int r = 0; r < 4; ++r)
            og[(hi * 4 + r) * FF + nf * 16 + lo] = acc[nf][r];
}

// ---------------------------------------------------------------------------
extern "C" void kernel_launch(void* const* d_in, const int* in_sizes, int n_in,
                              void* d_out, int out_size, void* d_ws, size_t ws_size,
                              hipStream_t stream)
{
    const float* x   = (const float*)d_in[0];
    const float* E1  = (const float*)d_in[1];
    const float* E2  = (const float*)d_in[2];
    const float* rw  = (const float*)d_in[3];
    const float* rb  = (const float*)d_in[4];
    // d_in[5] = outer_lambda: algebraically unused (outer == identity)
    const float* lq1 = (const float*)d_in[6];
    const float* lk1 = (const float*)d_in[7];
    const float* lq2 = (const float*)d_in[8];
    const float* lk2 = (const float*)d_in[9];
    const int*  bias = (const int*)d_in[10];

    float* ws    = (float*)d_ws;
    float* routeT = ws + ROUTET_OFF;
    __hip_bfloat16* E1cb = (__hip_bfloat16*)(ws + E1CB_OFF);
    __hip_bfloat16* E2sb = (__hip_bfloat16*)(ws + E2SB_OFF);
    __hip_bfloat16* xT   = (__hip_bfloat16*)(ws + XT_OFF);
    __hip_bfloat16* Mt   = (__hip_bfloat16*)(ws + MT_OFF);

    float* out      = (float*)d_out;
    float* topk_out = out + (long)BB * NN * FF;

    hipLaunchKernelGGL(router_kernel, dim3(256), dim3(128), 0, stream,
                       x, rw, rb, bias, routeT, topk_out);
    hipLaunchKernelGGL(e1_softmax_kernel, dim3(2048), dim3(256), 0, stream,
                       E1, lq1, lk1, lq2, lk2, E1cb);
    hipLaunchKernelGGL(e2_softmax_kernel, dim3(1024), dim3(256), 0, stream,
                       E2, E2sb);
    hipLaunchKernelGGL(xpose_kernel, dim3(64), dim3(256), 0, stream,
                       x, xT);
    hipLaunchKernelGGL(phaseA_mfma, dim3(1024), dim3(256), 0, stream,
                       E2sb, xT, Mt);
    hipLaunchKernelGGL(phaseB_mfma, dim3(512), dim3(256), 0, stream,
                       Mt, E1cb, routeT, out);
}

// Round 5
// 55.169 us; speedup vs baseline: 2.5933x; 1.2330x over previous
//
#include <hip/hip_runtime.h>
#include <hip/hip_bf16.h>

#define BB 64
#define NN 512
#define FF 64
#define KK 16
#define GG 32
#define TOPKN 4

typedef __attribute__((ext_vector_type(8))) __bf16 bf16x8;
typedef __attribute__((ext_vector_type(4))) float f32x4;

// workspace layout (float offsets)
#define ROUTET_OFF 0                               // fp32 [b][k][i]  = 524288 f
#define E1CB_OFF   (BB*KK*NN)                      // bf16 [e,k,i,d]  = 262144 f
#define E2SB_OFF   (E1CB_OFF + (2*KK*NN*GG)/2)     // bf16 1024x512   = 262144 f
#define XT_OFF     (E2SB_OFF + (2*KK*GG*NN)/2)     // bf16 [b][f][j]  = 1048576 f
#define MT_OFF     (XT_OFF + (BB*FF*NN)/2)         // bf16 [b][f][ked]= 2097152 f
// total ws floats = 4194304 (~16.8 MB)

// ---------------------------------------------------------------------------
// Kernel 1: router (fp64 accumulate for exact top-k ordering)
// ---------------------------------------------------------------------------
__global__ __launch_bounds__(128)
void router_kernel(const float* __restrict__ x, const float* __restrict__ rw,
                   const float* __restrict__ rb, const int* __restrict__ bias,
                   float* __restrict__ routeT, float* __restrict__ topk_out)
{
    __shared__ float rwl[KK * FF];
    __shared__ float rbl[KK];
    __shared__ float xl[128 * 65];

    const int t = threadIdx.x;
    for (int i = t; i < KK * FF; i += 128) rwl[i] = rw[i];
    if (t < KK) rbl[t] = rb[t];

    const long base = (long)blockIdx.x * 128 * FF;
    const float4* src = (const float4*)(x + base);
    for (int q = 0; q < 16; ++q) {
        int idx = t + q * 128;
        float4 v = src[idx];
        int row = idx >> 4;
        int fo = (idx & 15) * 4;
        xl[row * 65 + fo + 0] = v.x;
        xl[row * 65 + fo + 1] = v.y;
        xl[row * 65 + fo + 2] = v.z;
        xl[row * 65 + fo + 3] = v.w;
    }
    __syncthreads();

    float xr[FF];
#pragma unroll
    for (int f = 0; f < FF; ++f) xr[f] = xl[t * 65 + f];

    const double bf = (double)bias[0];
    double sigd[KK], selv[KK];
#pragma unroll
    for (int k = 0; k < KK; ++k) {
        double s = (double)rbl[k];
#pragma unroll
        for (int f = 0; f < FF; ++f)
            s += (double)rwl[k * FF + f] * (double)xr[f];
        double sg = 1.0 / (1.0 + exp(-s));
        sigd[k] = sg;
        selv[k] = sg + bf;
    }

    int idx4[TOPKN];
#pragma unroll
    for (int tt = 0; tt < TOPKN; ++tt) {
        double m = -1e300; int mi = 0;
#pragma unroll
        for (int k = 0; k < KK; ++k) {
            if (selv[k] > m) { m = selv[k]; mi = k; }
        }
        idx4[tt] = mi;
        selv[mi] = -1e300;
    }
    double ssum = 0.0;
#pragma unroll
    for (int tt = 0; tt < TOPKN; ++tt) ssum += sigd[idx4[tt]];

    float rv[KK];
#pragma unroll
    for (int k = 0; k < KK; ++k) rv[k] = 0.f;
#pragma unroll
    for (int tt = 0; tt < TOPKN; ++tt)
        rv[idx4[tt]] = (float)(sigd[idx4[tt]] / ssum);

    const long row = (long)blockIdx.x * 128 + t;
    const int b = (int)(row >> 9);
    const int n = (int)(row & 511);
#pragma unroll
    for (int k = 0; k < KK; ++k)
        routeT[((long)b * KK + k) * NN + n] = rv[k];

    float4 ti = make_float4((float)idx4[0], (float)idx4[1], (float)idx4[2], (float)idx4[3]);
    *(float4*)(topk_out + row * TOPKN) = ti;
}

// ---------------------------------------------------------------------------
// Kernel 2: E1 softmax over G, times coef[e], bf16 output [e,k,i,d]
// ---------------------------------------------------------------------------
__global__ __launch_bounds__(256)
void e1_softmax_kernel(const float* __restrict__ E1,
                       const float* __restrict__ lq1, const float* __restrict__ lk1,
                       const float* __restrict__ lq2, const float* __restrict__ lk2,
                       __hip_bfloat16* __restrict__ E1cb)
{
    const int t = threadIdx.x;
    const long row = (long)blockIdx.x * 8 + (t >> 5);
    const int l = t & 31;
    float val = E1[row * GG + l];
    float m = val;
#pragma unroll
    for (int s = 16; s >= 1; s >>= 1) m = fmaxf(m, __shfl_xor(m, s, 32));
    float ex = expf(val - m);
    float sum = ex;
#pragma unroll
    for (int s = 16; s >= 1; s >>= 1) sum += __shfl_xor(sum, s, 32);
    float sm = ex / sum;

    const int e = (int)(row >> 13);
    float coef = 1.0f;
    if (e) {
        float l1 = 0.f, l2 = 0.f;
#pragma unroll
        for (int i = 0; i < 64; ++i) {
            l1 = fmaf(lq1[i], lk1[i], l1);
            l2 = fmaf(lq2[i], lk2[i], l2);
        }
        const float lambda_init = 0.3555090675909692f;
        coef = -(expf(l1) - expf(l2) + lambda_init);
    }
    E1cb[row * GG + l] = __float2bfloat16(coef * sm);
}

// ---------------------------------------------------------------------------
// Kernel 3: E2 softmax over N=512, bf16 output rows (e*16+k)*32+d
// ---------------------------------------------------------------------------
__global__ __launch_bounds__(256)
void e2_softmax_kernel(const float* __restrict__ E2, __hip_bfloat16* __restrict__ E2sb)
{
    __shared__ float red[4];
    const int t = threadIdx.x;
    const long base = (long)blockIdx.x * NN;
    float v0 = E2[base + t], v1 = E2[base + t + 256];
    float m = fmaxf(v0, v1);
#pragma unroll
    for (int s = 32; s >= 1; s >>= 1) m = fmaxf(m, __shfl_xor(m, s));
    if ((t & 63) == 0) red[t >> 6] = m;
    __syncthreads();
    m = fmaxf(fmaxf(red[0], red[1]), fmaxf(red[2], red[3]));
    float e0 = expf(v0 - m), e1 = expf(v1 - m);
    float s2 = e0 + e1;
#pragma unroll
    for (int s = 32; s >= 1; s >>= 1) s2 += __shfl_xor(s2, s);
    __syncthreads();
    if ((t & 63) == 0) red[t >> 6] = s2;
    __syncthreads();
    s2 = red[0] + red[1] + red[2] + red[3];
    E2sb[base + t] = __float2bfloat16(e0 / s2);
    E2sb[base + t + 256] = __float2bfloat16(e1 / s2);
}

// ---------------------------------------------------------------------------
// Kernel 3b: x transpose to bf16: xT[b][f][j]. grid 512 = (b, chunk of 64 j)
// ---------------------------------------------------------------------------
__global__ __launch_bounds__(256)
void xpose_kernel(const float* __restrict__ x, __hip_bfloat16* __restrict__ xT)
{
    __shared__ float xl[64 * 65];
    const int t = threadIdx.x;
    const int b = blockIdx.x >> 3;
    const int j0 = (blockIdx.x & 7) * 64;
    const float* xb = x + (long)b * NN * FF;
    __hip_bfloat16* xo = xT + (long)b * FF * NN;

    const float4* src = (const float4*)(xb + (long)j0 * FF);
#pragma unroll
    for (int q = 0; q < 4; ++q) {
        int idx = t + q * 256;
        float4 v = src[idx];
        int j = idx >> 4;
        int f = (idx & 15) * 4;
        xl[j * 65 + f + 0] = v.x;
        xl[j * 65 + f + 1] = v.y;
        xl[j * 65 + f + 2] = v.z;
        xl[j * 65 + f + 3] = v.w;
    }
    __syncthreads();
#pragma unroll
    for (int q = 0; q < 16; ++q) {
        int idx = t + q * 256;
        int f = idx >> 6, j = idx & 63;
        xo[(long)f * NN + j0 + j] = __float2bfloat16(xl[j * 65 + f]);
    }
}

// ---------------------------------------------------------------------------
// Kernel 4 (phase A, MFMA): per (b,k): tile[64ed x 64f] = E2row . xT^T
// 2-phase pipeline: double-buffered LDS, STAGE(t+1) issued before compute(t),
// ONE __syncthreads per tile (drains vmcnt -> staged data ready, buffer free).
// epilogue: padded-LDS transpose -> Mt bf16 [b][f][k*64+ed]
// ---------------------------------------------------------------------------
__global__ __launch_bounds__(256)
void phaseA_mfma(const __hip_bfloat16* __restrict__ E2sb,
                 const __hip_bfloat16* __restrict__ xT,
                 __hip_bfloat16* __restrict__ Mt)
{
    __shared__ __align__(16) char smem[65536];  // 2 x (A 16KB | B 16KB)
    const int t = threadIdx.x;
    const int L = blockIdx.x;
    const int xc = L & 7, q = L >> 3;
    const int b = xc * 8 + (q >> 4), k = q & 15;
    const int wid = t >> 6, lane = t & 63;
    const int lo = lane & 15, hi = lane >> 4;

    const char* e2p = (const char*)E2sb;
    const char* xp  = (const char*)(xT + (long)b * FF * NN);

    auto stage = [&](int buf, int tile) {
        const int j0b = tile * 256;
#pragma unroll
        for (int qq = 0; qq < 4; ++qq) {
            const int Lb = (wid * 4 + qq) * 1024 + lane * 16;  // linear LDS byte
            const int ed = Lb >> 8;                            // 256B rows
            const int jb = (Lb & 255) ^ ((ed & 7) << 4);       // inverse-swizzled col
            const int rowA = ((ed >> 5) * 512) + k * 32 + (ed & 31);
            char* dbase = smem + buf * 32768 + (wid * 4 + qq) * 1024;
            __builtin_amdgcn_global_load_lds(
                (const __attribute__((address_space(1))) void*)(e2p + (long)rowA * 1024 + j0b + jb),
                (__attribute__((address_space(3))) void*)dbase, 16, 0, 0);
            __builtin_amdgcn_global_load_lds(
                (const __attribute__((address_space(1))) void*)(xp + (long)ed * 1024 + j0b + jb),
                (__attribute__((address_space(3))) void*)(dbase + 16384), 16, 0, 0);
        }
    };

    f32x4 acc[4] = {};
    int buf = 0;
    stage(0, 0);
    __syncthreads();

    for (int tile = 0; tile < 4; ++tile) {
        if (tile < 3) stage(buf ^ 1, tile + 1);
        const char* base = smem + buf * 32768;
#pragma unroll
        for (int ks = 0; ks < 4; ++ks) {
            const int cb = ks * 64 + hi * 16;
            const int arow = wid * 16 + lo;
            const int abyte = arow * 256 + (cb ^ ((arow & 7) << 4));
            bf16x8 a = *(const bf16x8*)(base + abyte);
#pragma unroll
            for (int nf = 0; nf < 4; ++nf) {
                const int brow = nf * 16 + lo;
                const int bbyte = 16384 + brow * 256 + (cb ^ ((brow & 7) << 4));
                bf16x8 bv = *(const bf16x8*)(base + bbyte);
                acc[nf] = __builtin_amdgcn_mfma_f32_16x16x32_bf16(a, bv, acc[nf], 0, 0, 0);
            }
        }
        __syncthreads();
        buf ^= 1;
    }

    // transpose via padded LDS tile [64 m][65] fp32, then bf16 write to Mt
    float* tl = (float*)smem;
#pragma unroll
    for (int nf = 0; nf < 4; ++nf)
#pragma unroll
        for (int r = 0; r < 4; ++r)
            tl[(wid * 16 + hi * 4 + r) * 65 + nf * 16 + lo] = acc[nf][r];
    __syncthreads();

    const int f = t >> 2;
    const int m0 = (t & 3) * 16;
    bf16x8 a0, a1;
#pragma unroll
    for (int j = 0; j < 8; ++j) {
        a0[j] = (__bf16)tl[(m0 + j) * 65 + f];
        a1[j] = (__bf16)tl[(m0 + 8 + j) * 65 + f];
    }
    __hip_bfloat16* dst = Mt + (long)b * 65536 + (long)f * 1024 + k * 64 + m0;
    *(bf16x8*)dst = a0;
    *(bf16x8*)(dst + 8) = a1;
}

// ---------------------------------------------------------------------------
// Kernel 5 (phase B, MFMA): per b: out[512 x 64] = W[512 x 1024] @ Mt^T
// W built on the fly: A-frag = E1cb segment * route weight (registers only).
// 2-phase pipeline over kk-PAIRS: dbuf 2x16KB, one barrier per pair (9 total).
// ---------------------------------------------------------------------------
__global__ __launch_bounds__(256)
void phaseB_mfma(const __hip_bfloat16* __restrict__ Mt,
                 const __hip_bfloat16* __restrict__ E1cb,
                 const float* __restrict__ routeT,
                 float* __restrict__ out)
{
    __shared__ __align__(16) char smem[32768];  // 2 bufs x (2 slices x 8KB)
    const int t = threadIdx.x;
    const int L = blockIdx.x;
    const int xc = L & 7, q = L >> 3;
    const int b = xc * 8 + (q >> 3);
    const int i0 = (q & 7) * 64;
    const int wid = t >> 6, lane = t & 63;
    const int lo = lane & 15, hi = lane >> 4;
    const int irow = i0 + wid * 16 + lo;

    float wk[KK];
    const float* rT = routeT + (long)b * KK * NN + irow;
#pragma unroll
    for (int k = 0; k < KK; ++k) wk[k] = rT[k * NN];

    const char* mtp = (const char*)(Mt + (long)b * 65536);

    auto stageB = [&](int buf, int kk2) {
#pragma unroll
        for (int h = 0; h < 2; ++h) {       // slice = kk2+h
#pragma unroll
            for (int g = 0; g < 2; ++g) {
                const int sbase = h * 8192 + wid * 2048 + g * 1024;  // wave-uniform
                const int Lb = sbase + lane * 16;
                const int ws_ = Lb & 8191;                   // byte within slice
                const int fr = ws_ >> 7;                     // f row (128B rows)
                const int cb = (ws_ & 127) ^ ((fr & 7) << 4);
                __builtin_amdgcn_global_load_lds(
                    (const __attribute__((address_space(1))) void*)(mtp + (long)fr * 2048 + (kk2 + h) * 128 + cb),
                    (__attribute__((address_space(3))) void*)(smem + buf * 16384 + sbase), 16, 0, 0);
            }
        }
    };

    f32x4 acc[4] = {};
    int buf = 0;
    stageB(0, 0);
    __syncthreads();

    for (int it = 0; it < 8; ++it) {
        const int kk2 = it * 2;
        if (it < 7) stageB(buf ^ 1, kk2 + 2);

        // A-frags for both kk of this pair (global reads, scaled by route wt)
        bf16x8 afr[2][2];
#pragma unroll
        for (int kkin = 0; kkin < 2; ++kkin) {
            const int kk = kk2 + kkin;
#pragma unroll
            for (int ks = 0; ks < 2; ++ks) {
                const long off = ((long)(ks * KK + kk) * NN + irow) * GG + hi * 8;
                bf16x8 v = *(const bf16x8*)(E1cb + off);
                bf16x8 r;
#pragma unroll
                for (int j = 0; j < 8; ++j)
                    r[j] = (__bf16)(wk[kk] * (float)v[j]);
                afr[kkin][ks] = r;
            }
        }

#pragma unroll
        for (int kkin = 0; kkin < 2; ++kkin) {
#pragma unroll
            for (int ks = 0; ks < 2; ++ks) {
#pragma unroll
                for (int nf = 0; nf < 4; ++nf) {
                    const int frow = nf * 16 + lo;
                    const int cb2 = (ks * 64 + hi * 16) ^ ((frow & 7) << 4);
                    bf16x8 bv = *(const bf16x8*)(smem + buf * 16384 + kkin * 8192 + frow * 128 + cb2);
                    acc[nf] = __builtin_amdgcn_mfma_f32_16x16x32_bf16(afr[kkin][ks], bv, acc[nf], 0, 0, 0);
                }
            }
        }
        __syncthreads();
        buf ^= 1;
    }

    float* og = out + ((long)b * NN + i0 + wid * 16) * FF;
#pragma unroll
    for (int nf = 0; nf < 4; ++nf)
#pragma unroll
        for (int r = 0; r < 4; ++r)
            og[(hi * 4 + r) * FF + nf * 16 + lo] = acc[nf][r];
}

// ---------------------------------------------------------------------------
extern "C" void kernel_launch(void* const* d_in, const int* in_sizes, int n_in,
                              void* d_out, int out_size, void* d_ws, size_t ws_size,
                              hipStream_t stream)
{
    const float* x   = (const float*)d_in[0];
    const float* E1  = (const float*)d_in[1];
    const float* E2  = (const float*)d_in[2];
    const float* rw  = (const float*)d_in[3];
    const float* rb  = (const float*)d_in[4];
    // d_in[5] = outer_lambda: algebraically unused (outer == identity)
    const float* lq1 = (const float*)d_in[6];
    const float* lk1 = (const float*)d_in[7];
    const float* lq2 = (const float*)d_in[8];
    const float* lk2 = (const float*)d_in[9];
    const int*  bias = (const int*)d_in[10];

    float* ws    = (float*)d_ws;
    float* routeT = ws + ROUTET_OFF;
    __hip_bfloat16* E1cb = (__hip_bfloat16*)(ws + E1CB_OFF);
    __hip_bfloat16* E2sb = (__hip_bfloat16*)(ws + E2SB_OFF);
    __hip_bfloat16* xT   = (__hip_bfloat16*)(ws + XT_OFF);
    __hip_bfloat16* Mt   = (__hip_bfloat16*)(ws + MT_OFF);

    float* out      = (float*)d_out;
    float* topk_out = out + (long)BB * NN * FF;

    hipLaunchKernelGGL(router_kernel, dim3(256), dim3(128), 0, stream,
                       x, rw, rb, bias, routeT, topk_out);
    hipLaunchKernelGGL(e1_softmax_kernel, dim3(2048), dim3(256), 0, stream,
                       E1, lq1, lk1, lq2, lk2, E1cb);
    hipLaunchKernelGGL(e2_softmax_kernel, dim3(1024), dim3(256), 0, stream,
                       E2, E2sb);
    hipLaunchKernelGGL(xpose_kernel, dim3(512), dim3(256), 0, stream,
                       x, xT);
    hipLaunchKernelGGL(phaseA_mfma, dim3(1024), dim3(256), 0, stream,
                       E2sb, xT, Mt);
    hipLaunchKernelGGL(phaseB_mfma, dim3(512), dim3(256), 0, stream,
                       Mt, E1cb, routeT, out);
}

// Round 6
// 47.895 us; speedup vs baseline: 2.9872x; 1.1519x over previous
//
#include <hip/hip_runtime.h>
#include <hip/hip_bf16.h>

#define BB 64
#define NN 512
#define FF 64
#define KK 16
#define GG 32
#define TOPKN 4

typedef __attribute__((ext_vector_type(8))) __bf16 bf16x8;
typedef __attribute__((ext_vector_type(4))) float f32x4;

// workspace layout (float offsets)
#define ROUTET_OFF 0                               // fp32 [b][k][i]  = 524288 f
#define E1CB_OFF   (BB*KK*NN)                      // bf16 [e,k,i,d]  = 262144 f
#define E2SB_OFF   (E1CB_OFF + (2*KK*NN*GG)/2)     // bf16 1024x512   = 262144 f
#define XT_OFF     (E2SB_OFF + (2*KK*GG*NN)/2)     // bf16 [b][f][j]  = 1048576 f
#define MT_OFF     (XT_OFF + (BB*FF*NN)/2)         // bf16 [b][f][ked]= 2097152 f

// ---------------------------------------------------------------------------
// Fused prep kernel, grid-sectioned:
//   [0,512):     xpose   x -> xT bf16 [b][f][j]
//   [512,1536):  e2 softmax -> E2sb bf16
//   [1536,2048): e1 softmax * coef -> E1cb bf16 (32 rows/block)
//   [2048,2176): router (fp64 ordering) -> routeT + topk
// ---------------------------------------------------------------------------
__global__ __launch_bounds__(256)
void prep_kernel(const float* __restrict__ x, const float* __restrict__ E1,
                 const float* __restrict__ E2, const float* __restrict__ rw,
                 const float* __restrict__ rb, const int* __restrict__ bias,
                 const float* __restrict__ lq1, const float* __restrict__ lk1,
                 const float* __restrict__ lq2, const float* __restrict__ lk2,
                 float* __restrict__ routeT, float* __restrict__ topk_out,
                 __hip_bfloat16* __restrict__ E1cb,
                 __hip_bfloat16* __restrict__ E2sb,
                 __hip_bfloat16* __restrict__ xT)
{
    __shared__ float sm[4224];   // union: xpose 64*65 | router rwl+rbl | e2 red
    const int B = blockIdx.x;
    const int t = threadIdx.x;

    if (B < 512) {
        // ---- xpose ----
        const int b = B >> 3;
        const int j0 = (B & 7) * 64;
        const float* xb = x + (long)b * NN * FF;
        __hip_bfloat16* xo = xT + (long)b * FF * NN;
        const float4* src = (const float4*)(xb + (long)j0 * FF);
#pragma unroll
        for (int q = 0; q < 4; ++q) {
            int idx = t + q * 256;
            float4 v = src[idx];
            int j = idx >> 4;
            int f = (idx & 15) * 4;
            sm[j * 65 + f + 0] = v.x;
            sm[j * 65 + f + 1] = v.y;
            sm[j * 65 + f + 2] = v.z;
            sm[j * 65 + f + 3] = v.w;
        }
        __syncthreads();
#pragma unroll
        for (int q = 0; q < 16; ++q) {
            int idx = t + q * 256;
            int f = idx >> 6, j = idx & 63;
            xo[(long)f * NN + j0 + j] = __float2bfloat16(sm[j * 65 + f]);
        }
    } else if (B < 1536) {
        // ---- e2 softmax (one row of 512 per block) ----
        const long base = (long)(B - 512) * NN;
        float v0 = E2[base + t], v1 = E2[base + t + 256];
        float m = fmaxf(v0, v1);
#pragma unroll
        for (int s = 32; s >= 1; s >>= 1) m = fmaxf(m, __shfl_xor(m, s));
        if ((t & 63) == 0) sm[t >> 6] = m;
        __syncthreads();
        m = fmaxf(fmaxf(sm[0], sm[1]), fmaxf(sm[2], sm[3]));
        float e0 = expf(v0 - m), e1 = expf(v1 - m);
        float s2 = e0 + e1;
#pragma unroll
        for (int s = 32; s >= 1; s >>= 1) s2 += __shfl_xor(s2, s);
        __syncthreads();
        if ((t & 63) == 0) sm[t >> 6] = s2;
        __syncthreads();
        s2 = sm[0] + sm[1] + sm[2] + sm[3];
        E2sb[base + t] = __float2bfloat16(e0 / s2);
        E2sb[base + t + 256] = __float2bfloat16(e1 / s2);
    } else if (B < 2048) {
        // ---- e1 softmax * coef (32 rows/block) ----
        const long base = (long)(B - 1536) * 32;
        const int e = (int)(base >> 13);     // all rows in block share e
        float coef = 1.0f;
        if (e) {
            float l1 = 0.f, l2 = 0.f;
#pragma unroll
            for (int i = 0; i < 64; ++i) {
                l1 = fmaf(lq1[i], lk1[i], l1);
                l2 = fmaf(lq2[i], lk2[i], l2);
            }
            const float lambda_init = 0.3555090675909692f;
            coef = -(expf(l1) - expf(l2) + lambda_init);
        }
        const int l = t & 31;
#pragma unroll
        for (int it = 0; it < 4; ++it) {
            const long row = base + it * 8 + (t >> 5);
            float val = E1[row * GG + l];
            float m = val;
#pragma unroll
            for (int s = 16; s >= 1; s >>= 1) m = fmaxf(m, __shfl_xor(m, s, 32));
            float ex = expf(val - m);
            float sum = ex;
#pragma unroll
            for (int s = 16; s >= 1; s >>= 1) sum += __shfl_xor(sum, s, 32);
            E1cb[row * GG + l] = __float2bfloat16(coef * (ex / sum));
        }
    } else {
        // ---- router (one row per thread, direct global x reads) ----
        float* rwl = sm;          // 1024
        float* rbl = sm + 1024;   // 16
        if (t < KK) rbl[t] = rb[t];
        for (int i = t; i < KK * FF; i += 256) rwl[i] = rw[i];
        __syncthreads();

        const long row = (long)(B - 2048) * 256 + t;
        float xr[FF];
        const float4* xrp = (const float4*)(x + row * FF);
#pragma unroll
        for (int c = 0; c < 16; ++c) {
            float4 v = xrp[c];
            xr[c * 4 + 0] = v.x; xr[c * 4 + 1] = v.y;
            xr[c * 4 + 2] = v.z; xr[c * 4 + 3] = v.w;
        }

        const double bf = (double)bias[0];
        double sigd[KK], selv[KK];
#pragma unroll
        for (int k = 0; k < KK; ++k) {
            double s = (double)rbl[k];
#pragma unroll
            for (int f = 0; f < FF; ++f)
                s += (double)rwl[k * FF + f] * (double)xr[f];
            double sg = 1.0 / (1.0 + exp(-s));
            sigd[k] = sg;
            selv[k] = sg + bf;
        }
        int idx4[TOPKN];
#pragma unroll
        for (int tt = 0; tt < TOPKN; ++tt) {
            double m = -1e300; int mi = 0;
#pragma unroll
            for (int k = 0; k < KK; ++k) {
                if (selv[k] > m) { m = selv[k]; mi = k; }
            }
            idx4[tt] = mi;
            selv[mi] = -1e300;
        }
        double ssum = 0.0;
#pragma unroll
        for (int tt = 0; tt < TOPKN; ++tt) ssum += sigd[idx4[tt]];
        float rv[KK];
#pragma unroll
        for (int k = 0; k < KK; ++k) rv[k] = 0.f;
#pragma unroll
        for (int tt = 0; tt < TOPKN; ++tt)
            rv[idx4[tt]] = (float)(sigd[idx4[tt]] / ssum);

        const int b = (int)(row >> 9);
        const int n = (int)(row & 511);
#pragma unroll
        for (int k = 0; k < KK; ++k)
            routeT[((long)b * KK + k) * NN + n] = rv[k];
        float4 ti = make_float4((float)idx4[0], (float)idx4[1], (float)idx4[2], (float)idx4[3]);
        *(float4*)(topk_out + row * TOPKN) = ti;
    }
}

// ---------------------------------------------------------------------------
// Kernel 4 (phase A, MFMA, 4x4 wave tile): grid 256 = (b, kg of 4 k's).
// Per block: A[256 r][512 j] (r=(e,kk,d)) x B=xT[64 f][512 j] -> 256x64.
// K-chunks of 64; dbuf 2x40KB LDS; 2-phase pipeline, 1 barrier/chunk.
// Each wave owns 64 r x 64 f: 8 ds_reads per 16 MFMA.
// Epilogue: padded-LDS transpose -> Mt bf16 [b][f][k*64+e*32+d]
// ---------------------------------------------------------------------------
__global__ __launch_bounds__(256, 2)
void phaseA_mfma(const __hip_bfloat16* __restrict__ E2sb,
                 const __hip_bfloat16* __restrict__ xT,
                 __hip_bfloat16* __restrict__ Mt)
{
    __shared__ __align__(16) char smem[81920];  // 2 x (A 32KB | B 8KB)
    const int t = threadIdx.x;
    const int L = blockIdx.x;
    const int xc = L & 7, q = L >> 3;           // q in [0,32)
    const int b = xc * 8 + (q >> 2);
    const int k0 = (q & 3) * 4;
    const int wid = t >> 6, lane = t & 63;
    const int lo = lane & 15, hi = lane >> 4;

    const char* e2p = (const char*)E2sb;
    const char* xp  = (const char*)(xT + (long)b * FF * NN);

    auto stage = [&](int buf, int c) {
        const int j0b = c * 128;    // byte offset within 1024B global row
        // A: 256 rows x 128B
#pragma unroll
        for (int qq = 0; qq < 8; ++qq) {
            const int lbase = qq * 4096 + wid * 1024;      // wave-uniform
            const int Lb = lbase + lane * 16;
            const int r = Lb >> 7;                          // 0..255
            const int cb = (Lb & 127) ^ ((r & 7) << 4);     // inverse swizzle
            const int grow = (r >> 7) * 512 + (k0 + ((r >> 5) & 3)) * 32 + (r & 31);
            __builtin_amdgcn_global_load_lds(
                (const __attribute__((address_space(1))) void*)(e2p + (long)grow * 1024 + j0b + cb),
                (__attribute__((address_space(3))) void*)(smem + buf * 40960 + lbase),
                16, 0, 0);
        }
        // B: 64 f rows x 128B
#pragma unroll
        for (int g = 0; g < 2; ++g) {
            const int lbase = g * 4096 + wid * 1024;        // within B region
            const int Lb = lbase + lane * 16;
            const int fr = Lb >> 7;                         // 0..63
            const int cb = (Lb & 127) ^ ((fr & 7) << 4);
            __builtin_amdgcn_global_load_lds(
                (const __attribute__((address_space(1))) void*)(xp + (long)fr * 1024 + j0b + cb),
                (__attribute__((address_space(3))) void*)(smem + buf * 40960 + 32768 + lbase),
                16, 0, 0);
        }
    };

    f32x4 acc[4][4] = {};
    int buf = 0;
    stage(0, 0);
    __syncthreads();

    for (int c = 0; c < 8; ++c) {
        if (c < 7) stage(buf ^ 1, c + 1);
        const char* base = smem + buf * 40960;
#pragma unroll
        for (int ks = 0; ks < 2; ++ks) {
            const int cbk = ks * 64 + hi * 16;
            bf16x8 a[4], bv[4];
#pragma unroll
            for (int am = 0; am < 4; ++am) {
                const int ar = wid * 64 + am * 16 + lo;
                a[am] = *(const bf16x8*)(base + ar * 128 + (cbk ^ ((ar & 7) << 4)));
            }
#pragma unroll
            for (int nf = 0; nf < 4; ++nf) {
                const int fr = nf * 16 + lo;
                bv[nf] = *(const bf16x8*)(base + 32768 + fr * 128 + (cbk ^ ((fr & 7) << 4)));
            }
#pragma unroll
            for (int am = 0; am < 4; ++am)
#pragma unroll
                for (int nf = 0; nf < 4; ++nf)
                    acc[am][nf] = __builtin_amdgcn_mfma_f32_16x16x32_bf16(a[am], bv[nf], acc[am][nf], 0, 0, 0);
        }
        __syncthreads();
        buf ^= 1;
    }

    // transpose via padded LDS [256 r][65] fp32 -> Mt bf16
    float* tl = (float*)smem;
#pragma unroll
    for (int am = 0; am < 4; ++am)
#pragma unroll
        for (int nf = 0; nf < 4; ++nf)
#pragma unroll
            for (int r = 0; r < 4; ++r)
                tl[(wid * 64 + am * 16 + hi * 4 + r) * 65 + nf * 16 + lo] = acc[am][nf][r];
    __syncthreads();

    const int f = t >> 2, qd = t & 3;
    __hip_bfloat16* mb = Mt + (long)b * 65536 + (long)f * 1024;
#pragma unroll
    for (int g = 0; g < 8; ++g) {
        const int rbase = qd * 64 + g * 8;
        bf16x8 v;
#pragma unroll
        for (int j = 0; j < 8; ++j)
            v[j] = (__bf16)tl[(rbase + j) * 65 + f];
        const int e = rbase >> 7, kk = (rbase >> 5) & 3, d0 = rbase & 31;
        *(bf16x8*)(mb + (k0 + kk) * 64 + e * 32 + d0) = v;
    }
}

// ---------------------------------------------------------------------------
// Kernel 5 (phase B, MFMA): per b: out[512 x 64] = W[512 x 1024] @ Mt^T
// W built on the fly: A-frag = E1cb segment * route weight (registers only).
// 2-phase pipeline over kk-PAIRS: dbuf 2x16KB, one barrier per pair.
// ---------------------------------------------------------------------------
__global__ __launch_bounds__(256)
void phaseB_mfma(const __hip_bfloat16* __restrict__ Mt,
                 const __hip_bfloat16* __restrict__ E1cb,
                 const float* __restrict__ routeT,
                 float* __restrict__ out)
{
    __shared__ __align__(16) char smem[32768];  // 2 bufs x (2 slices x 8KB)
    const int t = threadIdx.x;
    const int L = blockIdx.x;
    const int xc = L & 7, q = L >> 3;
    const int b = xc * 8 + (q >> 3);
    const int i0 = (q & 7) * 64;
    const int wid = t >> 6, lane = t & 63;
    const int lo = lane & 15, hi = lane >> 4;
    const int irow = i0 + wid * 16 + lo;

    float wk[KK];
    const float* rT = routeT + (long)b * KK * NN + irow;
#pragma unroll
    for (int k = 0; k < KK; ++k) wk[k] = rT[k * NN];

    const char* mtp = (const char*)(Mt + (long)b * 65536);

    auto stageB = [&](int buf, int kk2) {
#pragma unroll
        for (int h = 0; h < 2; ++h) {
#pragma unroll
            for (int g = 0; g < 2; ++g) {
                const int sbase = h * 8192 + wid * 2048 + g * 1024;  // wave-uniform
                const int Lb = sbase + lane * 16;
                const int ws_ = Lb & 8191;
                const int fr = ws_ >> 7;
                const int cb = (ws_ & 127) ^ ((fr & 7) << 4);
                __builtin_amdgcn_global_load_lds(
                    (const __attribute__((address_space(1))) void*)(mtp + (long)fr * 2048 + (kk2 + h) * 128 + cb),
                    (__attribute__((address_space(3))) void*)(smem + buf * 16384 + sbase), 16, 0, 0);
            }
        }
    };

    f32x4 acc[4] = {};
    int buf = 0;
    stageB(0, 0);
    __syncthreads();

    for (int it = 0; it < 8; ++it) {
        const int kk2 = it * 2;
        if (it < 7) stageB(buf ^ 1, kk2 + 2);

        bf16x8 afr[2][2];
#pragma unroll
        for (int kkin = 0; kkin < 2; ++kkin) {
            const int kk = kk2 + kkin;
#pragma unroll
            for (int ks = 0; ks < 2; ++ks) {
                const long off = ((long)(ks * KK + kk) * NN + irow) * GG + hi * 8;
                bf16x8 v = *(const bf16x8*)(E1cb + off);
                bf16x8 r;
#pragma unroll
                for (int j = 0; j < 8; ++j)
                    r[j] = (__bf16)(wk[kk] * (float)v[j]);
                afr[kkin][ks] = r;
            }
        }

#pragma unroll
        for (int kkin = 0; kkin < 2; ++kkin) {
#pragma unroll
            for (int ks = 0; ks < 2; ++ks) {
#pragma unroll
                for (int nf = 0; nf < 4; ++nf) {
                    const int frow = nf * 16 + lo;
                    const int cb2 = (ks * 64 + hi * 16) ^ ((frow & 7) << 4);
                    bf16x8 bv = *(const bf16x8*)(smem + buf * 16384 + kkin * 8192 + frow * 128 + cb2);
                    acc[nf] = __builtin_amdgcn_mfma_f32_16x16x32_bf16(afr[kkin][ks], bv, acc[nf], 0, 0, 0);
                }
            }
        }
        __syncthreads();
        buf ^= 1;
    }

    float* og = out + ((long)b * NN + i0 + wid * 16) * FF;
#pragma unroll
    for (int nf = 0; nf < 4; ++nf)
#pragma unroll
        for (int r = 0; r < 4; ++r)
            og[(hi * 4 + r) * FF + nf * 16 + lo] = acc[nf][r];
}

// ---------------------------------------------------------------------------
extern "C" void kernel_launch(void* const* d_in, const int* in_sizes, int n_in,
                              void* d_out, int out_size, void* d_ws, size_t ws_size,
                              hipStream_t stream)
{
    const float* x   = (const float*)d_in[0];
    const float* E1  = (const float*)d_in[1];
    const float* E2  = (const float*)d_in[2];
    const float* rw  = (const float*)d_in[3];
    const float* rb  = (const float*)d_in[4];
    // d_in[5] = outer_lambda: algebraically unused (outer == identity)
    const float* lq1 = (const float*)d_in[6];
    const float* lk1 = (const float*)d_in[7];
    const float* lq2 = (const float*)d_in[8];
    const float* lk2 = (const float*)d_in[9];
    const int*  bias = (const int*)d_in[10];

    float* ws    = (float*)d_ws;
    float* routeT = ws + ROUTET_OFF;
    __hip_bfloat16* E1cb = (__hip_bfloat16*)(ws + E1CB_OFF);
    __hip_bfloat16* E2sb = (__hip_bfloat16*)(ws + E2SB_OFF);
    __hip_bfloat16* xT   = (__hip_bfloat16*)(ws + XT_OFF);
    __hip_bfloat16* Mt   = (__hip_bfloat16*)(ws + MT_OFF);

    float* out      = (float*)d_out;
    float* topk_out = out + (long)BB * NN * FF;

    hipLaunchKernelGGL(prep_kernel, dim3(2176), dim3(256), 0, stream,
                       x, E1, E2, rw, rb, bias, lq1, lk1, lq2, lk2,
                       routeT, topk_out, E1cb, E2sb, xT);
    hipLaunchKernelGGL(phaseA_mfma, dim3(256), dim3(256), 0, stream,
                       E2sb, xT, Mt);
    hipLaunchKernelGGL(phaseB_mfma, dim3(512), dim3(256), 0, stream,
                       Mt, E1cb, routeT, out);
}